// Round 14
// baseline (259.642 us; speedup 1.0000x reference)
//
#include <hip/hip_runtime.h>
#include <math.h>

#define NANCH 16128      // 64*64*3 + 32*32*3 + 16*16*3
#define NSEG  84         // decode segments per image
#define SEGA  192        // anchors per segment
#define NB    16
#define NDET  100
#define SCORE_TH 0.25f
#define IOU_TH   0.5f
#define IMGSZ    512.0f

#define FUSED_THREADS 512
#define TOTAL_BLOCKS  (NB * NSEG)          // 1344
#define NMS_BLOCK0    (TOTAL_BLOCKS - NB)  // last 16 blocks run the NMS phase
#define DEC_DW4       (SEGA * 85 / 4)      // 4080 float4 = 63.75 KB LDS

#define KCAP   2048
#define NBUCK  64        // coarse score buckets: (score_bits>>18) - 0xFA0 in [0,64)
#define SEL_TARGET 256u
#define SORTCAP 1024

__device__ __constant__ float c_anchors[18] = {
    12.f,16.f, 19.f,36.f, 40.f,28.f,
    36.f,75.f, 76.f,55.f, 72.f,146.f,
    142.f,110.f, 192.f,243.f, 459.f,401.f
};

__device__ __forceinline__ float sigmoidf_(float x) {
    return 1.0f / (1.0f + expf(-x));
}

// Exact DIoU suppression test; roles: (B*) = accepted box, (c*) = candidate.
// Float expression order identical to the validated round-1..13 kernels (absmax 0).
__device__ __forceinline__ bool suppresses(float Bx, float By, float Bw, float Bh,
                                           float cx, float cy, float cw, float ch) {
    float b1minx = Bx - Bw * 0.5f, b1maxx = Bx + Bw * 0.5f;
    float b1miny = By - Bh * 0.5f, b1maxy = By + Bh * 0.5f;
    float b2minx = cx - cw * 0.5f, b2maxx = cx + cw * 0.5f;
    float b2miny = cy - ch * 0.5f, b2maxy = cy + ch * 0.5f;
    float iw = fmaxf(fminf(b1maxx, b2maxx) - fmaxf(b1minx, b2minx), 0.f);
    float ih = fmaxf(fminf(b1maxy, b2maxy) - fmaxf(b1miny, b2miny), 0.f);
    float inter = iw * ih;
    float uni   = Bw * Bh + cw * ch - inter;
    float iou   = inter / (uni + 1e-9f);
    float ex = fmaxf(b1maxx, b2maxx) - fminf(b1minx, b2minx);
    float ey = fmaxf(b1maxy, b2maxy) - fminf(b1miny, b2miny);
    float c2 = ex * ex + ey * ey + 1e-9f;
    float dx = Bx - cx, dy = By - cy;
    float diou = iou - (dx * dx + dy * dy) / c2;
    return diou > IOU_TH;
}

// 64-bucket threshold select (validated R10-R13).
__device__ __forceinline__ int select_bstar64(const unsigned int* hist, int b_hi,
                                              int lane, unsigned int* rem_out) {
    unsigned int cnt = (lane < b_hi) ? hist[lane] : 0u;
    unsigned int suf = cnt;
    #pragma unroll
    for (int off = 1; off < 64; off <<= 1) {
        unsigned int ov = __shfl_down(suf, off);
        if (lane + off < 64) suf += ov;
    }
    unsigned int remaining = __shfl(suf, 0);
    *rem_out = remaining;
    if (remaining == 0u) return b_hi;
    if (remaining <= (unsigned)SORTCAP) return 0;
    unsigned long long el = __ballot(suf >= SEL_TARGET);
    int bstar = 63 - __builtin_clzll(el);
    unsigned int pref  = __shfl(suf, bstar);
    unsigned int above = (bstar < 63) ? __shfl(suf, bstar + 1) : 0u;
    if (pref > (unsigned)SORTCAP && above > 0u) return bstar + 1;
    return bstar;
}

// key layout: [score_bits:32][16383-idx:14][class:7][0:11]
// u64 ascending == (score asc, idx desc); real key never 0.

__global__ __launch_bounds__(FUSED_THREADS)
void fused_kernel(const float* __restrict__ p0,
                  const float* __restrict__ p1,
                  const float* __restrict__ p2,
                  float4* __restrict__ boxes,
                  unsigned long long* __restrict__ keylist,
                  unsigned int* __restrict__ bhist,
                  unsigned int* __restrict__ ctr,
                  float* __restrict__ out) {
    __shared__ union {
        struct {
            float4 lds4[DEC_DW4];
            int wcnt[8];
            unsigned int lhist[NBUCK];
        } dec;
        struct {
            unsigned int hist[NBUCK];
            unsigned long long keyb[KCAP];
            float4 acc[NDET];
            float dets[NDET * 6];
            int wtot[8];
            unsigned long long wsupp[8];
            unsigned char smat[8][64];
            int ctrl[1];
        } nms;
    } sm;

    const int blk = blockIdx.x;
    const int tid = threadIdx.x;
    const int lane = tid & 63;
    const int wave = tid >> 6;

    // ================= DECODE PHASE (all 1344 blocks) =================
    {
        int b   = blk / NSEG;
        int seg = blk - b * NSEG;

        const float* src; int S, lgS, scale, loc;
        float stride;
        if (seg < 64)      { scale = 0; S = 64; lgS = 6; stride = 8.f;  src = p0; loc = seg * SEGA; }
        else if (seg < 80) { scale = 1; S = 32; lgS = 5; stride = 16.f; src = p1; loc = seg * SEGA - 12288; }
        else               { scale = 2; S = 16; lgS = 4; stride = 32.f; src = p2; loc = seg * SEGA - 15360; }

        // coalesced float4 staging with 512 threads (base 16B-aligned)
        const float4* s4 = (const float4*)(src + ((size_t)b * (S * S * 3) + loc) * 85);
        {
            int j = tid;
            #pragma unroll
            for (int r = 0; r < 7; ++r, j += FUSED_THREADS) sm.dec.lds4[j] = s4[j];
            if (j < DEC_DW4) sm.dec.lds4[j] = s4[j];
        }
        if (tid < NBUCK) sm.dec.lhist[tid] = 0u;
        __syncthreads();

        bool cand = false;
        unsigned long long key = 0ull;
        if (tid < SEGA) {
            const float* p = (const float*)sm.dec.lds4 + tid * 85;  // stride 85 -> conflict-free
            int local = loc + tid;
            int a    = local % 3;
            int cell = local / 3;
            int gj   = cell & (S - 1);
            int gi   = cell >> lgS;

            float tx = p[0], ty = p[1], tw = p[2], th = p[3], tobj = p[4];

            float bestl = p[5];
            int   bc    = 0;
            #pragma unroll 8
            for (int c = 1; c < 80; ++c) {
                float v = p[5 + c];
                if (v > bestl) { bestl = v; bc = c; }
            }

            float bx = ((sigmoidf_(tx) * 2.0f - 0.5f) + (float)gj) * stride;
            float by = ((sigmoidf_(ty) * 2.0f - 0.5f) + (float)gi) * stride;
            float sw = sigmoidf_(tw) * 2.0f; sw = sw * sw;
            float sh = sigmoidf_(th) * 2.0f; sh = sh * sh;
            float aw = c_anchors[scale * 6 + a * 2];
            float ah = c_anchors[scale * 6 + a * 2 + 1];
            float bw = sw * aw;
            float bh = sh * ah;

            bx = fminf(fmaxf(bx, 0.f), IMGSZ);
            by = fminf(fmaxf(by, 0.f), IMGSZ);
            bw = fminf(fmaxf(bw, 0.f), IMGSZ);
            bh = fminf(fmaxf(bh, 0.f), IMGSZ);

            float score = sigmoidf_(tobj) * sigmoidf_(bestl);
            if (score >= SCORE_TH) {
                cand = true;
                int gidx = seg * SEGA + tid;
                boxes[(size_t)b * NANCH + gidx] = make_float4(bx, by, bw, bh);
                key = ((unsigned long long)__float_as_uint(score) << 32)
                    | ((unsigned long long)(16383 - gidx) << 18)
                    | ((unsigned long long)bc << 11);
                int bu = (int)(__float_as_uint(score) >> 18) - 0xFA0;   // [0,64)
                bu = min(bu, NBUCK - 1);
                atomicAdd(&sm.dec.lhist[bu], 1u);
            }
            keylist[(size_t)b * NANCH + seg * SEGA + tid] = 0ull;  // zero-prefill slot
        }

        // segment-slotted compaction (candidates live in waves 0-2 only)
        unsigned long long m = __ballot(cand);
        if (lane == 0) sm.dec.wcnt[wave] = __popcll(m);
        __syncthreads();                    // wcnt + lhist + zero-prefill complete
        int base = 0;
        #pragma unroll
        for (int j = 0; j < 8; ++j) if (j < wave) base += sm.dec.wcnt[j];
        if (cand) {
            int pos = base + (int)__popcll(m & ((1ull << lane) - 1ull));
            keylist[(size_t)b * NANCH + seg * SEGA + pos] = key;
        }
        if (tid < NBUCK / 2)
            bhist[((size_t)b * NSEG + seg) * (NBUCK / 2) + tid] =
                (sm.dec.lhist[2 * tid] & 0xFFFFu) | (sm.dec.lhist[2 * tid + 1] << 16);
    }

    // ---- device-scope completion barrier ----
    __threadfence();                 // make this thread's global writes visible
    __syncthreads();                 // all threads fenced before the signal
    if (tid == 0) atomicAdd(ctr, 1u);
    if (blk < NMS_BLOCK0) return;    // pure-decode blocks exit

    if (tid == 0) {
        while (atomicAdd(ctr, 0u) < (unsigned)TOTAL_BLOCKS)
            __builtin_amdgcn_s_sleep(8);
        __threadfence();             // acquire: order subsequent reads
    }
    __syncthreads();

    // ================= NMS PHASE (last 16 blocks) =================
    const int b = blk - NMS_BLOCK0;

    const float4* bb = boxes + (size_t)b * NANCH;
    const unsigned long long* kl = keylist + (size_t)b * NANCH;
    float* o = out + (size_t)b * NDET * 6;

    if (tid < NBUCK) sm.nms.hist[tid] = 0u;
    if (tid == 0)    sm.nms.ctrl[0] = 0;
    __syncthreads();

    // sum the 84 per-block u16-packed histograms (one coalesced pass)
    {
        const unsigned int* bh = bhist + (size_t)b * NSEG * (NBUCK / 2);
        for (int i = tid; i < NSEG * (NBUCK / 2); i += FUSED_THREADS) {
            unsigned int v = bh[i];
            int bu = (i & (NBUCK / 2 - 1)) * 2;
            atomicAdd(&sm.nms.hist[bu],     v & 0xFFFFu);
            atomicAdd(&sm.nms.hist[bu + 1], v >> 16);
        }
    }
    __syncthreads();

    int b_hi = NBUCK;
    for (int round = 0; round < 64; ++round) {
        unsigned int remaining;
        int bstar = select_bstar64(sm.nms.hist, b_hi, lane, &remaining);
        int A0 = sm.nms.ctrl[0];
        if (remaining == 0u || A0 >= NDET) break;   // uniform exit
        __syncthreads();

        // ---- register-resident compact: no LDS atomics, one barrier ----
        int nsel;
        {
            unsigned long long kreg[32];
            #pragma unroll
            for (int k = 0; k < 32; ++k) {
                int i = tid + k * FUSED_THREADS;
                kreg[k] = (i < NANCH) ? kl[i] : 0ull;
            }
            unsigned int pm = 0;
            #pragma unroll
            for (int k = 0; k < 32; ++k) {
                int bu = (int)(kreg[k] >> 50) - 0xFA0;   // empty (0) -> fails
                bu = min(bu, NBUCK - 1);
                if (bu >= bstar && bu < b_hi) pm |= (1u << k);
            }
            int myc = __popc(pm);
            int inc = myc;
            #pragma unroll
            for (int off = 1; off < 64; off <<= 1) {
                int v = __shfl_up(inc, off);
                if (lane >= off) inc += v;
            }
            if (lane == 63) sm.nms.wtot[wave] = inc;
            __syncthreads();
            int wbase = 0, tot = 0;
            #pragma unroll
            for (int w2 = 0; w2 < 8; ++w2) {
                int v = sm.nms.wtot[w2];
                if (w2 < wave) wbase += v;
                tot += v;
            }
            int oo = wbase + (inc - myc);
            #pragma unroll
            for (int k = 0; k < 32; ++k) {
                if ((pm >> k) & 1u) { if (oo < KCAP) sm.nms.keyb[oo] = kreg[k]; ++oo; }
            }
            nsel = (tot > KCAP) ? KCAP : tot;
        }
        __syncthreads();

        int N = 64; while (N < nsel) N <<= 1;

        if (nsel > 0) {
            if (nsel <= 512) {
                unsigned long long v = (tid < nsel) ? sm.nms.keyb[tid] : 0ull;
                for (int k2 = 2; k2 <= N; k2 <<= 1) {
                    for (int j2 = k2 >> 1; j2 > 0; j2 >>= 1) {
                        unsigned long long pv;
                        if (j2 < 64) {
                            pv = __shfl_xor(v, j2);
                        } else {
                            __syncthreads();
                            sm.nms.keyb[tid] = v;
                            __syncthreads();
                            pv = sm.nms.keyb[tid ^ j2];
                        }
                        bool dir     = ((tid & k2) == 0);
                        bool keepmin = (((tid & j2) == 0) == dir);
                        bool take    = keepmin ? (pv < v) : (pv > v);
                        if (take) v = pv;
                    }
                }
                __syncthreads();
                sm.nms.keyb[tid] = v;
                __syncthreads();
            } else if (nsel <= 1024) {
                const int e0 = tid, e1 = tid + 512;
                unsigned long long v0 = sm.nms.keyb[e0];
                unsigned long long v1 = (e1 < nsel) ? sm.nms.keyb[e1] : 0ull;
                for (int k2 = 2; k2 <= 1024; k2 <<= 1) {
                    for (int j2 = k2 >> 1; j2 > 0; j2 >>= 1) {
                        if (j2 == 512) {
                            unsigned long long lo = (v0 < v1) ? v0 : v1;
                            unsigned long long hi = (v0 < v1) ? v1 : v0;
                            v0 = lo; v1 = hi;
                        } else if (j2 >= 64) {
                            __syncthreads();
                            sm.nms.keyb[e0] = v0; sm.nms.keyb[e1] = v1;
                            __syncthreads();
                            unsigned long long q0 = sm.nms.keyb[e0 ^ j2];
                            unsigned long long q1 = sm.nms.keyb[e1 ^ j2];
                            bool dir0 = ((e0 & k2) == 0);
                            bool dir1 = ((e1 & k2) == 0);
                            bool km0  = (((e0 & j2) == 0) == dir0);
                            bool km1  = (((e1 & j2) == 0) == dir1);
                            if (km0 ? (q0 < v0) : (q0 > v0)) v0 = q0;
                            if (km1 ? (q1 < v1) : (q1 > v1)) v1 = q1;
                        } else {
                            unsigned long long q0 = __shfl_xor(v0, j2);
                            unsigned long long q1 = __shfl_xor(v1, j2);
                            bool dir0 = ((e0 & k2) == 0);
                            bool dir1 = ((e1 & k2) == 0);
                            bool km0  = (((e0 & j2) == 0) == dir0);
                            bool km1  = (((e1 & j2) == 0) == dir1);
                            if (km0 ? (q0 < v0) : (q0 > v0)) v0 = q0;
                            if (km1 ? (q1 < v1) : (q1 > v1)) v1 = q1;
                        }
                    }
                }
                __syncthreads();
                sm.nms.keyb[e0] = v0; sm.nms.keyb[e1] = v1;
                __syncthreads();
                N = 1024;
            } else {
                for (int t2 = tid; t2 < N; t2 += FUSED_THREADS)
                    if (t2 >= nsel) sm.nms.keyb[t2] = 0ull;
                for (int k2 = 2; k2 <= N; k2 <<= 1) {
                    for (int j2 = k2 >> 1; j2 > 0; j2 >>= 1) {
                        __syncthreads();
                        for (int t2 = tid; t2 < N; t2 += FUSED_THREADS) {
                            int p2 = t2 ^ j2;
                            if (p2 > t2) {
                                unsigned long long av = sm.nms.keyb[t2], bv = sm.nms.keyb[p2];
                                bool up = ((t2 & k2) == 0);
                                if (up ? (av > bv) : (av < bv)) { sm.nms.keyb[t2] = bv; sm.nms.keyb[p2] = av; }
                            }
                        }
                    }
                }
                __syncthreads();
            }

            // ---- ordered greedy scan: parallel pre-check + 64x64 matrix; bit-op resolve ----
            {
                int A = sm.nms.ctrl[0];
                int cb = N - 1;
                int pos = cb - lane;
                unsigned long long key = (pos >= 0) ? sm.nms.keyb[pos] : 0ull;
                float4 c = make_float4(0.f, 0.f, 0.f, 0.f);
                if (key != 0ull) c = bb[16383 - (int)((key >> 18) & 0x3FFFull)];

                while (A < NDET) {
                    bool valid = (key != 0ull);
                    unsigned long long vmask = __ballot(valid);
                    if (vmask == 0ull) break;

                    int ncb = cb - 64;
                    unsigned long long nkey = 0ull;
                    float4 nc = make_float4(0.f, 0.f, 0.f, 0.f);
                    if (ncb >= 0) {
                        int npos = ncb - lane;
                        nkey = (npos >= 0) ? sm.nms.keyb[npos] : 0ull;
                        if (nkey != 0ull) nc = bb[16383 - (int)((nkey >> 18) & 0x3FFFull)];
                    }

                    bool supp = false;
                    for (int i = wave; i < A; i += 8) {
                        float4 a = sm.nms.acc[i];
                        if (valid && suppresses(a.x, a.y, a.z, a.w, c.x, c.y, c.z, c.w))
                            supp = true;
                    }
                    sm.nms.wsupp[wave] = __ballot(supp);

                    {
                        unsigned int part = 0;
                        #pragma unroll
                        for (int k = 0; k < 8; ++k) {
                            int i = wave * 8 + k;
                            float Bx = __shfl(c.x, i), By = __shfl(c.y, i);
                            float Bw = __shfl(c.z, i), Bh = __shfl(c.w, i);
                            bool s = ((vmask >> i) & 1ull) && valid &&
                                     suppresses(Bx, By, Bw, Bh, c.x, c.y, c.z, c.w);
                            part |= (unsigned int)s << k;
                        }
                        sm.nms.smat[wave][lane] = (unsigned char)part;
                    }
                    __syncthreads();

                    if (wave == 0) {
                        unsigned long long smk = sm.nms.wsupp[0] | sm.nms.wsupp[1]
                                               | sm.nms.wsupp[2] | sm.nms.wsupp[3]
                                               | sm.nms.wsupp[4] | sm.nms.wsupp[5]
                                               | sm.nms.wsupp[6] | sm.nms.wsupp[7];
                        unsigned long long bym = 0ull;
                        #pragma unroll
                        for (int w2 = 0; w2 < 8; ++w2)
                            bym |= (unsigned long long)sm.nms.smat[w2][lane] << (8 * w2);

                        int Aw = A;
                        bool alive = valid && !((smk >> lane) & 1ull);
                        float scv = __uint_as_float((unsigned int)(key >> 32));
                        float cls = (float)((key >> 11) & 0x7Full);
                        unsigned long long mm = __ballot(alive);
                        while (mm && Aw < NDET) {
                            int l = (int)__builtin_ctzll(mm);
                            if (lane == l) {
                                sm.nms.acc[Aw] = c;
                                sm.nms.dets[Aw * 6 + 0] = c.x;
                                sm.nms.dets[Aw * 6 + 1] = c.y;
                                sm.nms.dets[Aw * 6 + 2] = c.z;
                                sm.nms.dets[Aw * 6 + 3] = c.w;
                                sm.nms.dets[Aw * 6 + 4] = scv;
                                sm.nms.dets[Aw * 6 + 5] = cls;
                                alive = false;
                            }
                            if ((bym >> l) & 1ull) alive = false;
                            Aw++;
                            mm = __ballot(alive);
                        }
                        if (lane == 0) sm.nms.ctrl[0] = Aw;
                    }
                    __syncthreads();
                    A = sm.nms.ctrl[0];
                    if (ncb < 0) break;
                    cb = ncb; key = nkey; c = nc;
                }
            }
        }
        __syncthreads();
        if (bstar >= b_hi) break;    // safety
        b_hi = bstar;
    }

    __syncthreads();
    int A = sm.nms.ctrl[0];
    for (int i = tid; i < NDET * 6; i += FUSED_THREADS)
        if (i >= A * 6) sm.nms.dets[i] = 0.0f;
    __syncthreads();
    for (int i = tid; i < NDET * 6; i += FUSED_THREADS) o[i] = sm.nms.dets[i];
}

extern "C" void kernel_launch(void* const* d_in, const int* in_sizes, int n_in,
                              void* d_out, int out_size, void* d_ws, size_t ws_size,
                              hipStream_t stream) {
    const float* p0 = (const float*)d_in[0];
    const float* p1 = (const float*)d_in[1];
    const float* p2 = (const float*)d_in[2];
    float* out = (float*)d_out;

    char* ws = (char*)d_ws;
    size_t off = 0;
    float4*             boxes   = (float4*)(ws + off);             off += (size_t)NB * NANCH * sizeof(float4);
    unsigned long long* keylist = (unsigned long long*)(ws + off); off += (size_t)NB * NANCH * sizeof(unsigned long long);
    unsigned int*       bhist   = (unsigned int*)(ws + off);       off += (size_t)NB * NSEG * (NBUCK / 2) * sizeof(unsigned int);
    unsigned int*       ctr     = (unsigned int*)(ws + off);

    hipMemsetAsync(ctr, 0, sizeof(unsigned int), stream);
    fused_kernel<<<TOTAL_BLOCKS, FUSED_THREADS, 0, stream>>>(p0, p1, p2, boxes, keylist, bhist, ctr, out);
}

// Round 15
// 60.484 us; speedup vs baseline: 4.2927x; 4.2927x over previous
//
#include <hip/hip_runtime.h>
#include <math.h>

#define NANCH 16128      // 64*64*3 + 32*32*3 + 16*16*3
#define NSEG  168        // decode segments per image (96 anchors each)
#define SEGA  96
#define NB    16
#define NDET  100
#define SCORE_TH 0.25f
#define IOU_TH   0.5f
#define IMGSZ    512.0f

#define DEC_THREADS 256
#define DEC_DW4     (SEGA * 85 / 4)   // 2040 float4 = 31.9 KB LDS -> 4-5 blocks/CU

#define NMS_THREADS 512
#define KCAP   2048
#define NBUCK  64        // coarse score buckets: (score_bits>>18) - 0xFA0 in [0,64)
#define SEL_TARGET 256u
#define SORTCAP 1024     // largest prefix the fast/hybrid sorts handle

__device__ __constant__ float c_anchors[18] = {
    12.f,16.f, 19.f,36.f, 40.f,28.f,
    36.f,75.f, 76.f,55.f, 72.f,146.f,
    142.f,110.f, 192.f,243.f, 459.f,401.f
};

__device__ __forceinline__ float sigmoidf_(float x) {
    return 1.0f / (1.0f + expf(-x));
}

// Exact DIoU suppression test; roles: (B*) = accepted box, (c*) = candidate.
// Float expression order identical to the validated round-1..13 kernels (absmax 0).
__device__ __forceinline__ bool suppresses(float Bx, float By, float Bw, float Bh,
                                           float cx, float cy, float cw, float ch) {
    float b1minx = Bx - Bw * 0.5f, b1maxx = Bx + Bw * 0.5f;
    float b1miny = By - Bh * 0.5f, b1maxy = By + Bh * 0.5f;
    float b2minx = cx - cw * 0.5f, b2maxx = cx + cw * 0.5f;
    float b2miny = cy - ch * 0.5f, b2maxy = cy + ch * 0.5f;
    float iw = fmaxf(fminf(b1maxx, b2maxx) - fmaxf(b1minx, b2minx), 0.f);
    float ih = fmaxf(fminf(b1maxy, b2maxy) - fmaxf(b1miny, b2miny), 0.f);
    float inter = iw * ih;
    float uni   = Bw * Bh + cw * ch - inter;
    float iou   = inter / (uni + 1e-9f);
    float ex = fmaxf(b1maxx, b2maxx) - fminf(b1minx, b2minx);
    float ey = fmaxf(b1maxy, b2maxy) - fminf(b1miny, b2miny);
    float c2 = ex * ex + ey * ey + 1e-9f;
    float dx = Bx - cx, dy = By - cy;
    float diou = iou - (dx * dx + dy * dy) / c2;
    return diou > IOU_TH;
}

// 64-bucket threshold select (validated R10-R13).
__device__ __forceinline__ int select_bstar64(const unsigned int* hist, int b_hi,
                                              int lane, unsigned int* rem_out) {
    unsigned int cnt = (lane < b_hi) ? hist[lane] : 0u;
    unsigned int suf = cnt;                       // inclusive suffix over lanes >= l
    #pragma unroll
    for (int off = 1; off < 64; off <<= 1) {
        unsigned int ov = __shfl_down(suf, off);
        if (lane + off < 64) suf += ov;
    }
    unsigned int remaining = __shfl(suf, 0);
    *rem_out = remaining;
    if (remaining == 0u) return b_hi;
    if (remaining <= (unsigned)SORTCAP) return 0;
    unsigned long long el = __ballot(suf >= SEL_TARGET);
    int bstar = 63 - __builtin_clzll(el);
    unsigned int pref  = __shfl(suf, bstar);
    unsigned int above = (bstar < 63) ? __shfl(suf, bstar + 1) : 0u;
    if (pref > (unsigned)SORTCAP && above > 0u) return bstar + 1;  // defer fat bucket
    return bstar;
}

// key layout: [score_bits:32][16383-idx:14][class:7][0:11]
// u64 ascending == (score asc, idx desc); real key never 0 (0 marks empty slots).

__global__ __launch_bounds__(DEC_THREADS)
void decode_kernel(const float* __restrict__ p0,
                   const float* __restrict__ p1,
                   const float* __restrict__ p2,
                   float4* __restrict__ boxes,
                   unsigned long long* __restrict__ keylist,
                   unsigned int* __restrict__ bhist) {
    __shared__ float4 lds4[DEC_DW4];
    __shared__ int wcnt[4];
    __shared__ unsigned int lhist[NBUCK];

    int blk = blockIdx.x;
    int b   = blk / NSEG;
    int seg = blk - b * NSEG;

    const float* src; int S, lgS, scale, loc;
    float stride;
    if (seg < 128)      { scale = 0; S = 64; lgS = 6; stride = 8.f;  src = p0; loc = seg * SEGA; }
    else if (seg < 160) { scale = 1; S = 32; lgS = 5; stride = 16.f; src = p1; loc = seg * SEGA - 12288; }
    else                { scale = 2; S = 16; lgS = 4; stride = 32.f; src = p2; loc = seg * SEGA - 15360; }

    // coalesced float4 staging (base = multiple of 8160 floats -> 16B aligned)
    const float4* s4 = (const float4*)(src + ((size_t)b * (S * S * 3) + loc) * 85);
    {
        int j = threadIdx.x;
        #pragma unroll
        for (int r = 0; r < 7; ++r, j += DEC_THREADS) lds4[j] = s4[j];
        if (j < DEC_DW4) lds4[j] = s4[j];
    }
    if (threadIdx.x < NBUCK) lhist[threadIdx.x] = 0u;
    __syncthreads();

    int t = threadIdx.x;
    bool cand = false;
    unsigned long long key = 0ull;
    if (t < SEGA) {
        const float* p = (const float*)lds4 + t * 85;   // stride 85 (odd) -> conflict-free
        int local = loc + t;
        int a    = local % 3;
        int cell = local / 3;
        int gj   = cell & (S - 1);
        int gi   = cell >> lgS;

        float tx = p[0], ty = p[1], tw = p[2], th = p[3], tobj = p[4];

        float bestl = p[5];
        int   bc    = 0;
        #pragma unroll 8
        for (int c = 1; c < 80; ++c) {
            float v = p[5 + c];
            if (v > bestl) { bestl = v; bc = c; }
        }

        float bx = ((sigmoidf_(tx) * 2.0f - 0.5f) + (float)gj) * stride;
        float by = ((sigmoidf_(ty) * 2.0f - 0.5f) + (float)gi) * stride;
        float sw = sigmoidf_(tw) * 2.0f; sw = sw * sw;
        float sh = sigmoidf_(th) * 2.0f; sh = sh * sh;
        float aw = c_anchors[scale * 6 + a * 2];
        float ah = c_anchors[scale * 6 + a * 2 + 1];
        float bw = sw * aw;
        float bh = sh * ah;

        bx = fminf(fmaxf(bx, 0.f), IMGSZ);
        by = fminf(fmaxf(by, 0.f), IMGSZ);
        bw = fminf(fmaxf(bw, 0.f), IMGSZ);
        bh = fminf(fmaxf(bh, 0.f), IMGSZ);

        float score = sigmoidf_(tobj) * sigmoidf_(bestl);
        if (score >= SCORE_TH) {
            cand = true;
            int gidx = seg * SEGA + t;
            boxes[(size_t)b * NANCH + gidx] = make_float4(bx, by, bw, bh);
            key = ((unsigned long long)__float_as_uint(score) << 32)
                | ((unsigned long long)(16383 - gidx) << 18)
                | ((unsigned long long)bc << 11);
            int bu = (int)(__float_as_uint(score) >> 18) - 0xFA0;   // [0,64) for [0.25,1]
            bu = min(bu, NBUCK - 1);
            atomicAdd(&lhist[bu], 1u);      // LDS only — no global atomics anywhere
        }
        // zero-prefill this segment's slot t (separated from key writes by barrier)
        keylist[(size_t)b * NANCH + seg * SEGA + t] = 0ull;
    }

    // segment-slotted compaction (no global placement atomics, no counts array)
    unsigned long long m = __ballot(cand);
    int lane = t & 63, w = t >> 6;
    if (lane == 0) wcnt[w] = __popcll(m);
    __syncthreads();                        // wcnt + lhist + zero-prefill complete
    int base = 0;
    #pragma unroll
    for (int j = 0; j < 4; ++j) if (j < w) base += wcnt[j];
    if (cand) {
        int pos = base + (int)__popcll(m & ((1ull << lane) - 1ull));
        keylist[(size_t)b * NANCH + seg * SEGA + pos] = key;
    }
    // per-block histogram, u16-packed, written unconditionally (no memset needed)
    if (t < NBUCK / 2)
        bhist[((size_t)b * NSEG + seg) * (NBUCK / 2) + t] =
            (lhist[2 * t] & 0xFFFFu) | (lhist[2 * t + 1] << 16);
}

// One block (512 thr) per image: sum bhist -> threshold -> register-compact ->
// sort -> scan (parallel pre-check + parallel 64x64 matrix, bit-ops-only resolve).
__global__ __launch_bounds__(NMS_THREADS)
void nms_kernel(const float4* __restrict__ boxes,
                const unsigned long long* __restrict__ keylist,
                const unsigned int* __restrict__ bhist,
                float* __restrict__ out) {
    int b    = blockIdx.x;
    int tid  = threadIdx.x;
    int lane = tid & 63;
    int wave = tid >> 6;

    const float4* bb = boxes + (size_t)b * NANCH;
    const unsigned long long* kl = keylist + (size_t)b * NANCH;
    float* o = out + (size_t)b * NDET * 6;

    __shared__ unsigned int       hist[NBUCK];
    __shared__ unsigned long long keyb[KCAP];
    __shared__ float4             acc[NDET];
    __shared__ float              dets[NDET * 6];
    __shared__ int                wtot[8];
    __shared__ unsigned long long wsupp[8];
    __shared__ unsigned char      smat[8][64];   // chunk suppression matrix, 8-bit slices
    __shared__ int                ctrl[1];       // accepted count A

    if (tid < NBUCK) hist[tid] = 0u;
    if (tid == 0)    ctrl[0] = 0;
    __syncthreads();

    // sum the 168 per-block u16-packed histograms (one coalesced pass)
    {
        const unsigned int* bh = bhist + (size_t)b * NSEG * (NBUCK / 2);
        for (int i = tid; i < NSEG * (NBUCK / 2); i += NMS_THREADS) {
            unsigned int v = bh[i];
            int bu = (i & (NBUCK / 2 - 1)) * 2;
            atomicAdd(&hist[bu],     v & 0xFFFFu);
            atomicAdd(&hist[bu + 1], v >> 16);
        }
    }
    __syncthreads();

    int b_hi = NBUCK;
    for (int round = 0; round < 64; ++round) {
        unsigned int remaining;
        int bstar = select_bstar64(hist, b_hi, lane, &remaining);   // all waves redundant
        int A0 = ctrl[0];
        if (remaining == 0u || A0 >= NDET) break;   // uniform exit
        __syncthreads();   // keyb reuse safe (prior round's reads done)

        // ---- register-resident compact: no LDS atomics, one barrier ----
        int nsel;
        {
            unsigned long long kreg[32];
            #pragma unroll
            for (int k = 0; k < 32; ++k) {
                int i = tid + k * NMS_THREADS;
                kreg[k] = (i < NANCH) ? kl[i] : 0ull;
            }
            unsigned int pm = 0;
            #pragma unroll
            for (int k = 0; k < 32; ++k) {
                int bu = (int)(kreg[k] >> 50) - 0xFA0;   // empty (0) -> -4000 -> fails
                bu = min(bu, NBUCK - 1);
                if (bu >= bstar && bu < b_hi) pm |= (1u << k);
            }
            int myc = __popc(pm);
            int inc = myc;                                // wave inclusive prefix scan
            #pragma unroll
            for (int off = 1; off < 64; off <<= 1) {
                int v = __shfl_up(inc, off);
                if (lane >= off) inc += v;
            }
            if (lane == 63) wtot[wave] = inc;
            __syncthreads();
            int wbase = 0, tot = 0;
            #pragma unroll
            for (int w2 = 0; w2 < 8; ++w2) {
                int v = wtot[w2];
                if (w2 < wave) wbase += v;
                tot += v;
            }
            int oo = wbase + (inc - myc);
            #pragma unroll
            for (int k = 0; k < 32; ++k) {
                if ((pm >> k) & 1u) { if (oo < KCAP) keyb[oo] = kreg[k]; ++oo; }
            }
            nsel = (tot > KCAP) ? KCAP : tot;
        }
        __syncthreads();

        int N = 64; while (N < nsel) N <<= 1;

        if (nsel > 0) {
            if (nsel <= 512) {
                // ---- validated fast path: 1 elem/thread, shfl for j2<64 ----
                unsigned long long v = (tid < nsel) ? keyb[tid] : 0ull;
                for (int k2 = 2; k2 <= N; k2 <<= 1) {
                    for (int j2 = k2 >> 1; j2 > 0; j2 >>= 1) {
                        unsigned long long pv;
                        if (j2 < 64) {
                            pv = __shfl_xor(v, j2);
                        } else {
                            __syncthreads();
                            keyb[tid] = v;
                            __syncthreads();
                            pv = keyb[tid ^ j2];
                        }
                        bool dir     = ((tid & k2) == 0);
                        bool keepmin = (((tid & j2) == 0) == dir);
                        bool take    = keepmin ? (pv < v) : (pv > v);
                        if (take) v = pv;
                    }
                }
                __syncthreads();
                keyb[tid] = v;
                __syncthreads();
            } else if (nsel <= 1024) {
                // ---- hybrid 1024: 2 elems/thread ----
                const int e0 = tid, e1 = tid + 512;
                unsigned long long v0 = keyb[e0];
                unsigned long long v1 = (e1 < nsel) ? keyb[e1] : 0ull;
                for (int k2 = 2; k2 <= 1024; k2 <<= 1) {
                    for (int j2 = k2 >> 1; j2 > 0; j2 >>= 1) {
                        if (j2 == 512) {
                            unsigned long long lo = (v0 < v1) ? v0 : v1;
                            unsigned long long hi = (v0 < v1) ? v1 : v0;
                            v0 = lo; v1 = hi;
                        } else if (j2 >= 64) {
                            __syncthreads();
                            keyb[e0] = v0; keyb[e1] = v1;
                            __syncthreads();
                            unsigned long long q0 = keyb[e0 ^ j2];
                            unsigned long long q1 = keyb[e1 ^ j2];
                            bool dir0 = ((e0 & k2) == 0);
                            bool dir1 = ((e1 & k2) == 0);
                            bool km0  = (((e0 & j2) == 0) == dir0);
                            bool km1  = (((e1 & j2) == 0) == dir1);
                            if (km0 ? (q0 < v0) : (q0 > v0)) v0 = q0;
                            if (km1 ? (q1 < v1) : (q1 > v1)) v1 = q1;
                        } else {
                            unsigned long long q0 = __shfl_xor(v0, j2);
                            unsigned long long q1 = __shfl_xor(v1, j2);
                            bool dir0 = ((e0 & k2) == 0);
                            bool dir1 = ((e1 & k2) == 0);
                            bool km0  = (((e0 & j2) == 0) == dir0);
                            bool km1  = (((e1 & j2) == 0) == dir1);
                            if (km0 ? (q0 < v0) : (q0 > v0)) v0 = q0;
                            if (km1 ? (q1 < v1) : (q1 > v1)) v1 = q1;
                        }
                    }
                }
                __syncthreads();
                keyb[e0] = v0; keyb[e1] = v1;
                __syncthreads();
                N = 1024;
            } else {
                // ---- general LDS bitonic fallback (pathological fat bucket) ----
                for (int t2 = tid; t2 < N; t2 += NMS_THREADS)
                    if (t2 >= nsel) keyb[t2] = 0ull;
                for (int k2 = 2; k2 <= N; k2 <<= 1) {
                    for (int j2 = k2 >> 1; j2 > 0; j2 >>= 1) {
                        __syncthreads();
                        for (int t2 = tid; t2 < N; t2 += NMS_THREADS) {
                            int p2 = t2 ^ j2;
                            if (p2 > t2) {
                                unsigned long long av = keyb[t2], bv = keyb[p2];
                                bool up = ((t2 & k2) == 0);
                                if (up ? (av > bv) : (av < bv)) { keyb[t2] = bv; keyb[p2] = av; }
                            }
                        }
                    }
                }
                __syncthreads();
            }

            // ---- ordered greedy scan: every wave holds the identical chunk; ----
            // ---- parallel pre-check + parallel 64x64 matrix; bit-op resolve ----
            {
                int A = ctrl[0];
                int cb = N - 1;
                int pos = cb - lane;
                unsigned long long key = (pos >= 0) ? keyb[pos] : 0ull;
                float4 c = make_float4(0.f, 0.f, 0.f, 0.f);
                if (key != 0ull) c = bb[16383 - (int)((key >> 18) & 0x3FFFull)];

                while (A < NDET) {
                    bool valid = (key != 0ull);
                    unsigned long long vmask = __ballot(valid);   // identical in all waves
                    if (vmask == 0ull) break;

                    // prefetch next chunk (hides behind pre-check + matrix)
                    int ncb = cb - 64;
                    unsigned long long nkey = 0ull;
                    float4 nc = make_float4(0.f, 0.f, 0.f, 0.f);
                    if (ncb >= 0) {
                        int npos = ncb - lane;
                        nkey = (npos >= 0) ? keyb[npos] : 0ull;
                        if (nkey != 0ull) nc = bb[16383 - (int)((nkey >> 18) & 0x3FFFull)];
                    }

                    // parallel pre-check vs accepted: wave w handles acc[w], acc[w+8], ...
                    bool supp = false;
                    for (int i = wave; i < A; i += 8) {
                        float4 a = acc[i];
                        if (valid && suppresses(a.x, a.y, a.z, a.w, c.x, c.y, c.z, c.w))
                            supp = true;
                    }
                    wsupp[wave] = __ballot(supp);

                    // parallel 64x64 intra-chunk matrix: thread (w,j) tests i in [8w,8w+8)
                    {
                        unsigned int part = 0;
                        #pragma unroll
                        for (int k = 0; k < 8; ++k) {
                            int i = wave * 8 + k;
                            float Bx = __shfl(c.x, i), By = __shfl(c.y, i);
                            float Bw = __shfl(c.z, i), Bh = __shfl(c.w, i);
                            bool s = ((vmask >> i) & 1ull) && valid &&
                                     suppresses(Bx, By, Bw, Bh, c.x, c.y, c.z, c.w);
                            part |= (unsigned int)s << k;
                        }
                        smat[wave][lane] = (unsigned char)part;
                    }
                    __syncthreads();

                    if (wave == 0) {
                        unsigned long long sm = wsupp[0] | wsupp[1] | wsupp[2] | wsupp[3]
                                              | wsupp[4] | wsupp[5] | wsupp[6] | wsupp[7];
                        unsigned long long bym = 0ull;   // who suppresses ME (by chunk lane)
                        #pragma unroll
                        for (int w2 = 0; w2 < 8; ++w2)
                            bym |= (unsigned long long)smat[w2][lane] << (8 * w2);

                        int Aw = A;
                        bool alive = valid && !((sm >> lane) & 1ull);
                        float scv = __uint_as_float((unsigned int)(key >> 32));
                        float cls = (float)((key >> 11) & 0x7Full);
                        unsigned long long mm = __ballot(alive);
                        while (mm && Aw < NDET) {
                            int l = (int)__builtin_ctzll(mm);  // highest-key survivor
                            if (lane == l) {
                                acc[Aw] = c;
                                dets[Aw * 6 + 0] = c.x;
                                dets[Aw * 6 + 1] = c.y;
                                dets[Aw * 6 + 2] = c.z;
                                dets[Aw * 6 + 3] = c.w;
                                dets[Aw * 6 + 4] = scv;
                                dets[Aw * 6 + 5] = cls;
                                alive = false;
                            }
                            if ((bym >> l) & 1ull) alive = false;  // precomputed DIoU
                            Aw++;
                            mm = __ballot(alive);
                        }
                        if (lane == 0) ctrl[0] = Aw;
                    }
                    __syncthreads();
                    A = ctrl[0];
                    if (ncb < 0) break;
                    cb = ncb; key = nkey; c = nc;
                }
            }
        }
        __syncthreads();
        if (bstar >= b_hi) break;    // safety
        b_hi = bstar;
    }

    __syncthreads();
    int A = ctrl[0];
    for (int i = tid; i < NDET * 6; i += NMS_THREADS)
        if (i >= A * 6) dets[i] = 0.0f;
    __syncthreads();
    for (int i = tid; i < NDET * 6; i += NMS_THREADS) o[i] = dets[i];
}

extern "C" void kernel_launch(void* const* d_in, const int* in_sizes, int n_in,
                              void* d_out, int out_size, void* d_ws, size_t ws_size,
                              hipStream_t stream) {
    const float* p0 = (const float*)d_in[0];
    const float* p1 = (const float*)d_in[1];
    const float* p2 = (const float*)d_in[2];
    float* out = (float*)d_out;

    char* ws = (char*)d_ws;
    size_t off = 0;
    float4*             boxes   = (float4*)(ws + off);             off += (size_t)NB * NANCH * sizeof(float4);
    unsigned long long* keylist = (unsigned long long*)(ws + off); off += (size_t)NB * NANCH * sizeof(unsigned long long);
    unsigned int*       bhist   = (unsigned int*)(ws + off);       // NB*NSEG*32 u32, fully rewritten each launch

    decode_kernel<<<NB * NSEG, DEC_THREADS, 0, stream>>>(p0, p1, p2, boxes, keylist, bhist);
    nms_kernel<<<NB, NMS_THREADS, 0, stream>>>(boxes, keylist, bhist, out);
}